// Round 6
// baseline (74.583 us; speedup 1.0000x reference)
//
#include <hip/hip_runtime.h>

// Mixture-of-64-tiny-experts, fp32, packed-pair (2 samples per thread lane-half).
// R5: (a) subnets split 32/32 across two wave-groups of a 512-thread block
// (restores 8 waves/SIMD), partials combined via LDS; (b) weights stored as
// duplicated pairs {w,w} so v_pk_fma_f32 takes them straight from an SGPR
// pair (s_load_dwordx2) with no v_mov broadcast duplication.

#define NSUB 64
#define L2E2 2.8853900817779268f   // 2*log2(e)
#define L2E  1.4426950408889634f   // log2(e)

typedef float v2f __attribute__((ext_vector_type(2)));

__device__ __forceinline__ v2f pk_fma(v2f a, v2f b, v2f c) {
    return __builtin_elementwise_fma(a, b, c);
}
__device__ __forceinline__ v2f sp(float s) { return v2f{s, s}; }

// tanhshrink(a) = (a-1) + 2*rcp(exp2(2L*a)+1)
__device__ __forceinline__ v2f tanhshrink_v(v2f a) {
    v2f s = a * L2E2;
    v2f e;
    e.x = __builtin_amdgcn_exp2f(s.x);
    e.y = __builtin_amdgcn_exp2f(s.y);
    v2f ep = e + 1.0f;
    v2f r;
    r.x = __builtin_amdgcn_rcpf(ep.x);
    r.y = __builtin_amdgcn_rcpf(ep.y);
    return pk_fma(sp(2.0f), r, a - 1.0f);
}

// tanh from pre-scaled input s = 2*log2e*raw
__device__ __forceinline__ v2f tanh_scaled_v(v2f s) {
    v2f e;
    e.x = __builtin_amdgcn_exp2f(s.x);
    e.y = __builtin_amdgcn_exp2f(s.y);
    v2f ep = e + 1.0f;
    v2f r;
    r.x = __builtin_amdgcn_rcpf(ep.x);
    r.y = __builtin_amdgcn_rcpf(ep.y);
    return pk_fma(sp(-2.0f), r, sp(1.0f));
}

// Packed per-subnet params as DUPLICATED PAIRS, 96 floats (48 pairs):
// pair idx: [0:24) W1 (4x6) | [24:28) b1 | [28:36) W2*2L | [36:38) b2*2L
//           [38:44) Gw2*L | [44] Gb2*L | [45:48) pad
__global__ void pack_kernel(const float* __restrict__ W1, const float* __restrict__ b1,
                            const float* __restrict__ W2, const float* __restrict__ b2,
                            const float* __restrict__ Gw2, const float* __restrict__ Gb2,
                            float* __restrict__ ws)
{
    int s = threadIdx.x;
    if (s >= NSUB) return;
    float* f = ws + s * 96;
    for (int i = 0; i < 24; ++i) { float v = W1[s * 24 + i];        f[2*i] = v;        f[2*i+1] = v; }
    for (int i = 0; i < 4;  ++i) { float v = b1[s * 4 + i];         f[48+2*i] = v;     f[48+2*i+1] = v; }
    for (int i = 0; i < 8;  ++i) { float v = W2[s * 8 + i] * L2E2;  f[56+2*i] = v;     f[56+2*i+1] = v; }
    for (int i = 0; i < 2;  ++i) { float v = b2[s * 2 + i] * L2E2;  f[72+2*i] = v;     f[72+2*i+1] = v; }
    for (int i = 0; i < 6;  ++i) { float v = Gw2[s * 6 + i] * L2E;  f[76+2*i] = v;     f[76+2*i+1] = v; }
    { float v = Gb2[s] * L2E; f[88] = v; f[89] = v; }
    f[90] = 0.f; f[91] = 0.f; f[92] = 0.f; f[93] = 0.f; f[94] = 0.f; f[95] = 0.f;
}

__global__ __launch_bounds__(512) void moe_kernel(
    const float* __restrict__ x,
    const float* __restrict__ wpack,
    const float* __restrict__ Gw1, const float* __restrict__ Gb1,
    float* __restrict__ out)
{
    int tid = threadIdx.x;
    int q = tid & 255;                     // sample-pair slot within block
    int half = tid >> 8;                   // 0: subnets 0-31, 1: subnets 32-63
    int sbase = __builtin_amdgcn_readfirstlane(half * 32);  // wave-uniform
    long p = (long)blockIdx.x * 256 + q;   // sample-pair index

    const float4* xv = (const float4*)(x + p * 12);
    float4 a0 = xv[0];
    float4 a1 = xv[1];
    float4 a2 = xv[2];
    v2f xa[6] = { v2f{a0.x, a1.z}, v2f{a0.y, a1.w}, v2f{a0.z, a2.x},
                  v2f{a0.w, a2.y}, v2f{a1.x, a2.z}, v2f{a1.y, a2.w} };

    // ---- gating hidden (duplicated in both halves; 6x6, small) ----
    v2f ga[6];
#pragma unroll
    for (int j = 0; j < 6; ++j) {
        v2f s = sp(Gb1[j]);
#pragma unroll
        for (int i = 0; i < 6; ++i)
            s = pk_fma(sp(Gw1[j * 6 + i]), xa[i], s);
        ga[j] = tanhshrink_v(s);
    }

    // ---- 32-subnet loop (this half's share) ----
    v2f acc0 = sp(0.f), acc1 = sp(0.f), accE = sp(0.f);

#pragma unroll 2
    for (int s = sbase; s < sbase + 32; ++s) {
        const v2f* f2 = (const v2f*)(wpack + s * 96);   // 48 duplicated pairs

        v2f h[4];
#pragma unroll
        for (int j = 0; j < 4; ++j) {
            v2f t = f2[24 + j];
#pragma unroll
            for (int i = 0; i < 6; ++i)
                t = pk_fma(f2[j * 6 + i], xa[i], t);
            h[j] = tanhshrink_v(t);
        }

        v2f o0 = f2[36], o1 = f2[37];   // pre-scaled by 2*log2e
#pragma unroll
        for (int j = 0; j < 4; ++j) {
            o0 = pk_fma(f2[28 + j], h[j], o0);
            o1 = pk_fma(f2[32 + j], h[j], o1);
        }
        o0 = tanh_scaled_v(o0);
        o1 = tanh_scaled_v(o1);

        v2f la = f2[44];                // pre-scaled by log2e
#pragma unroll
        for (int j = 0; j < 6; ++j)
            la = pk_fma(f2[38 + j], ga[j], la);
        v2f ea;
        ea.x = __builtin_amdgcn_exp2f(la.x);
        ea.y = __builtin_amdgcn_exp2f(la.y);

        accE = accE + ea;
        acc0 = pk_fma(ea, o0, acc0);
        acc1 = pk_fma(ea, o1, acc1);
    }

    // ---- combine halves through LDS ----
    __shared__ v2f lds[256 * 3];
    if (half) {
        lds[q * 3 + 0] = accE;
        lds[q * 3 + 1] = acc0;
        lds[q * 3 + 2] = acc1;
    }
    __syncthreads();
    if (!half) {
        accE = accE + lds[q * 3 + 0];
        acc0 = acc0 + lds[q * 3 + 1];
        acc1 = acc1 + lds[q * 3 + 2];
        v2f ra;
        ra.x = __builtin_amdgcn_rcpf(accE.x);
        ra.y = __builtin_amdgcn_rcpf(accE.y);
        acc0 = acc0 * ra;
        acc1 = acc1 * ra;
        float4 r;
        r.x = acc0.x; r.y = acc1.x; r.z = acc0.y; r.w = acc1.y;
        ((float4*)&out[p * 4])[0] = r;
    }
}

extern "C" void kernel_launch(void* const* d_in, const int* in_sizes, int n_in,
                              void* d_out, int out_size, void* d_ws, size_t ws_size,
                              hipStream_t stream) {
    const float* x   = (const float*)d_in[0];
    const float* W1  = (const float*)d_in[1];
    const float* b1  = (const float*)d_in[2];
    const float* W2  = (const float*)d_in[3];
    const float* b2  = (const float*)d_in[4];
    const float* Gw1 = (const float*)d_in[5];
    const float* Gb1 = (const float*)d_in[6];
    const float* Gw2 = (const float*)d_in[7];
    const float* Gb2 = (const float*)d_in[8];
    float* out = (float*)d_out;
    float* ws  = (float*)d_ws;   // 64*96*4 = 24 KB

    pack_kernel<<<1, 64, 0, stream>>>(W1, b1, W2, b2, Gw2, Gb2, ws);

    // 262144 sample-pairs; block = 512 threads covers 256 pairs (two halves)
    const int threads = 512;
    const int blocks = 262144 / 256;  // 1024
    moe_kernel<<<blocks, threads, 0, stream>>>(x, ws, Gw1, Gb1, out);
}